// Round 1
// baseline (530.456 us; speedup 1.0000x reference)
//
#include <hip/hip_runtime.h>
#include <hip/hip_bf16.h>
#include <stdint.h>

#define S_LEN 2048
#define NHEAD 16
#define BATCH 4

typedef __attribute__((ext_vector_type(8))) short short8;
typedef __attribute__((ext_vector_type(4))) float f32x4;
typedef __attribute__((ext_vector_type(4))) unsigned short u16x4;
typedef __attribute__((ext_vector_type(2))) unsigned short u16x2;

__device__ __forceinline__ unsigned short f2bf(float f) {
  union { float f; uint32_t u; } a; a.f = f;
  uint32_t r = (a.u + 0x7fff + ((a.u >> 16) & 1)) >> 16;
  return (unsigned short)r;
}
__device__ __forceinline__ float bf2f(unsigned short u) {
  union { uint32_t u; float f; } a; a.u = ((uint32_t)u) << 16;
  return a.f;
}

__device__ __forceinline__ void gload16(const void* g, void* l) {
  __builtin_amdgcn_global_load_lds(
      (const __attribute__((address_space(1))) void*)g,
      (__attribute__((address_space(3))) void*)l, 16, 0, 0);
}

// ---------------- fp32 -> bf16 convert ----------------
__global__ void k_cvt(const float* __restrict__ src, unsigned short* __restrict__ dst, int n4) {
  int i = blockIdx.x * blockDim.x + threadIdx.x;
  if (i < n4) {
    float4 v = ((const float4*)src)[i];
    u16x4 o;
    o[0] = f2bf(v.x); o[1] = f2bf(v.y); o[2] = f2bf(v.z); o[3] = f2bf(v.w);
    ((u16x4*)dst)[i] = o;
  }
}

// ---------------- NT GEMM: C[M,N] = A[M,K] * B[N,K]^T, bf16 in, fp32 acc ----------------
// grid: (N/128, M/128), block 256 (4 waves, 2x2), BK=64
template<int OUTF32>
__global__ __launch_bounds__(256) void k_gemm_nt(
    const unsigned short* __restrict__ A, const unsigned short* __restrict__ B,
    void* __restrict__ Cp, int K, int ldc)
{
  __shared__ unsigned short lA[128 * 64];
  __shared__ unsigned short lB[128 * 64];
  const int tid = threadIdx.x;
  const int w = tid >> 6, lane = tid & 63;
  const int wm = w >> 1, wn = w & 1;
  const int l15 = lane & 15, lg = lane >> 4;
  const int row0 = blockIdx.y * 128, col0 = blockIdx.x * 128;

  f32x4 acc[4][4] = {};

  const size_t rsb = (size_t)K * 2;  // row stride bytes

  for (int k0 = 0; k0 < K; k0 += 64) {
#pragma unroll
    for (int it = 0; it < 4; ++it) {
      int f = w * 4096 + it * 1024 + lane * 16;
      int r = f >> 7, cb = f & 127;
      gload16((const char*)A + (size_t)(row0 + r) * rsb + k0 * 2 + cb,
              (char*)lA + (w * 4096 + it * 1024));
      gload16((const char*)B + (size_t)(col0 + r) * rsb + k0 * 2 + cb,
              (char*)lB + (w * 4096 + it * 1024));
    }
    __syncthreads();
#pragma unroll
    for (int ks = 0; ks < 2; ++ks) {
      short8 af[4], bg[4];
#pragma unroll
      for (int i = 0; i < 4; ++i) {
        int rowa = wm * 64 + i * 16 + l15;
        af[i] = *(const short8*)((const char*)lA + rowa * 128 + ks * 64 + lg * 16);
        int rowb = wn * 64 + i * 16 + l15;
        bg[i] = *(const short8*)((const char*)lB + rowb * 128 + ks * 64 + lg * 16);
      }
#pragma unroll
      for (int i = 0; i < 4; ++i)
#pragma unroll
        for (int j = 0; j < 4; ++j)
          acc[i][j] = __builtin_amdgcn_mfma_f32_16x16x32_bf16(af[i], bg[j], acc[i][j], 0, 0, 0);
    }
    __syncthreads();
  }

#pragma unroll
  for (int i = 0; i < 4; ++i)
#pragma unroll
    for (int j = 0; j < 4; ++j)
#pragma unroll
      for (int r = 0; r < 4; ++r) {
        int row = row0 + wm * 64 + i * 16 + lg * 4 + r;
        int col = col0 + wn * 64 + j * 16 + l15;
        float v = acc[i][j][r];
        if (OUTF32) ((float*)Cp)[(size_t)row * ldc + col] = v;
        else ((unsigned short*)Cp)[(size_t)row * ldc + col] = f2bf(v);
      }
}

// ---------------- RoPE in-place on fused qkv [8192][3072], cols 0..2047 ----------------
__global__ void k_rope(unsigned short* __restrict__ qkv, const int* __restrict__ pos) {
  int idx = blockIdx.x * 256 + threadIdx.x;  // 8192*1024 threads, one pair each
  int row = idx >> 10;
  int c = idx & 1023;
  int which = c >> 9;        // 0 = Q cols, 1 = K cols
  int cp = c & 511;          // pair index within the 1024-wide tensor
  int p = cp & 31;           // within-head pair index
  int s = row & (S_LEN - 1);
  float fp = (float)pos[s];
  // 10000^(-p/32) = 2^(-p * log2(10000)/32)
  float inv = exp2f(-(float)p * 0.41524101186092029f);
  float ang = fp * inv;
  float sn, cs;
  __sincosf(ang, &sn, &cs);
  size_t off = (size_t)row * 3072 + which * 1024 + cp * 2;
  u16x2 v = *(u16x2*)(qkv + off);
  float x0 = bf2f(v[0]), x1 = bf2f(v[1]);
  u16x2 o;
  o[0] = f2bf(cs * x0 - sn * x1);
  o[1] = f2bf(sn * x0 + cs * x1);
  *(u16x2*)(qkv + off) = o;
}

// ---------------- causal flash attention ----------------
// grid: (32 qblocks, 64 b*h), block 256. Wave w owns q-rows [qb+w*16, qb+w*16+16).
__global__ __launch_bounds__(256) void k_attn(const unsigned short* __restrict__ qkv,
                                              unsigned short* __restrict__ O) {
  __shared__ unsigned short lK[64 * 64];      // [krow][dk], XOR-swizzled bytes
  __shared__ unsigned short lV[64 * 72];      // transposed: [d][kk], stride 72
  __shared__ unsigned short lP[4][16 * 72];   // per-wave P tile [qrow][kk], stride 72

  const int tid = threadIdx.x, w = tid >> 6, lane = tid & 63;
  const int l15 = lane & 15, lg = lane >> 4;
  const int bh = blockIdx.y, b = bh >> 4, h = bh & 15;
  const int qb = ((int)gridDim.x - 1 - (int)blockIdx.x) * 64;

  const size_t rstride = 3072;

  // Q fragments (A-layout): row = l15, k = ks*32 + lg*8 .. +8
  short8 qf[2];
  {
    int qrow = qb + w * 16 + l15;
    const unsigned short* qp = qkv + (size_t)(b * S_LEN + qrow) * rstride + h * 64 + lg * 8;
    qf[0] = *(const short8*)qp;
    qf[1] = *(const short8*)(qp + 32);
  }

  float mrun[4], lrun[4];
  f32x4 oacc[4];
#pragma unroll
  for (int r = 0; r < 4; ++r) { mrun[r] = -3e38f; lrun[r] = 0.f; }
#pragma unroll
  for (int j = 0; j < 4; ++j) oacc[j] = (f32x4){0.f, 0.f, 0.f, 0.f};

  const int ntiles = (qb >> 6) + 1;
  for (int t = 0; t < ntiles; ++t) {
    const int kv = t * 64;
    __syncthreads();  // previous tile's LDS reads done
    // stage K: linear LDS dest, inverse-swizzled global source
#pragma unroll
    for (int it = 0; it < 2; ++it) {
      int f = w * 2048 + it * 1024 + lane * 16;
      int r = f >> 7;
      int cb = (f ^ ((r & 7) << 4)) & 127;
      gload16((const char*)qkv + ((size_t)(b * S_LEN + kv + r) * rstride + 1024 + h * 64) * 2 + cb,
              (char*)lK + (w * 2048 + it * 1024));
    }
    // stage V transposed: [d][kk]
#pragma unroll
    for (int it = 0; it < 2; ++it) {
      int idx = it * 256 + tid;  // 0..511
      int kk = idx >> 3, c = (idx & 7) * 8;
      short8 vv = *(const short8*)(qkv + (size_t)(b * S_LEN + kv + kk) * rstride + 2048 + h * 64 + c);
#pragma unroll
      for (int e = 0; e < 8; ++e)
        lV[(c + e) * 72 + kk] = (unsigned short)vv[e];
    }
    __syncthreads();  // K landed (vmcnt), V writes visible

    // QK^T : S[16 q][64 k]
    f32x4 sf[4] = {};
#pragma unroll
    for (int ks = 0; ks < 2; ++ks) {
#pragma unroll
      for (int jf = 0; jf < 4; ++jf) {
        int krow = jf * 16 + l15;
        int g = krow * 128 + ks * 64 + lg * 16;
        int a = g ^ ((krow & 7) << 4);
        short8 kb = *(const short8*)((const char*)lK + a);
        sf[jf] = __builtin_amdgcn_mfma_f32_16x16x32_bf16(qf[ks], kb, sf[jf], 0, 0, 0);
      }
    }

    // online softmax (rows = lg*4 + r within wave tile)
    const bool diag = (kv == qb);
    float pv[4][4], alpha[4];
#pragma unroll
    for (int r = 0; r < 4; ++r) {
      int qrow = qb + w * 16 + lg * 4 + r;
      float mx = -3e38f;
#pragma unroll
      for (int jf = 0; jf < 4; ++jf) {
        float v = sf[jf][r] * 0.125f;
        if (diag) {
          int col = kv + jf * 16 + l15;
          if (col > qrow) v = -3e38f;
        }
        pv[jf][r] = v;
        mx = fmaxf(mx, v);
      }
      mx = fmaxf(mx, __shfl_xor(mx, 1, 16));
      mx = fmaxf(mx, __shfl_xor(mx, 2, 16));
      mx = fmaxf(mx, __shfl_xor(mx, 4, 16));
      mx = fmaxf(mx, __shfl_xor(mx, 8, 16));
      float mn = fmaxf(mrun[r], mx);
      alpha[r] = __expf(mrun[r] - mn);
      mrun[r] = mn;
      float ps = 0.f;
#pragma unroll
      for (int jf = 0; jf < 4; ++jf) {
        float e = __expf(pv[jf][r] - mn);
        pv[jf][r] = e;
        ps += e;
      }
      ps += __shfl_xor(ps, 1, 16);
      ps += __shfl_xor(ps, 2, 16);
      ps += __shfl_xor(ps, 4, 16);
      ps += __shfl_xor(ps, 8, 16);
      lrun[r] = lrun[r] * alpha[r] + ps;
    }
    // rescale O accumulator
#pragma unroll
    for (int j = 0; j < 4; ++j)
#pragma unroll
      for (int r = 0; r < 4; ++r)
        oacc[j][r] *= alpha[r];

    // write P (bf16) to per-wave LDS: [row = lg*4+r][col = jf*16+l15]
    unsigned short* pw = &lP[w][0];
#pragma unroll
    for (int jf = 0; jf < 4; ++jf)
#pragma unroll
      for (int r = 0; r < 4; ++r)
        pw[(lg * 4 + r) * 72 + jf * 16 + l15] = f2bf(pv[jf][r]);

    // PV: O[16 q][64 d] += P[16 q][64 k] * V[64 k][64 d]
#pragma unroll
    for (int ks = 0; ks < 2; ++ks) {
      short8 pa = *(const short8*)(pw + l15 * 72 + ks * 32 + lg * 8);
#pragma unroll
      for (int j = 0; j < 4; ++j) {
        short8 vb = *(const short8*)(&lV[(j * 16 + l15) * 72 + ks * 32 + lg * 8]);
        oacc[j] = __builtin_amdgcn_mfma_f32_16x16x32_bf16(pa, vb, oacc[j], 0, 0, 0);
      }
    }
  }

  // write O (bf16) [8192][1024]
#pragma unroll
  for (int j = 0; j < 4; ++j)
#pragma unroll
    for (int r = 0; r < 4; ++r) {
      int qrow = qb + w * 16 + lg * 4 + r;
      float v = oacc[j][r] / lrun[r];
      O[(size_t)(b * S_LEN + qrow) * 1024 + h * 64 + j * 16 + l15] = f2bf(v);
    }
}

extern "C" void kernel_launch(void* const* d_in, const int* in_sizes, int n_in,
                              void* d_out, int out_size, void* d_ws, size_t ws_size,
                              hipStream_t stream) {
  const float* x  = (const float*)d_in[0];
  const int* pos  = (const int*)d_in[1];
  const float* wq = (const float*)d_in[2];
  const float* wk = (const float*)d_in[3];
  const float* wv = (const float*)d_in[4];
  const float* wo = (const float*)d_in[5];
  float* out = (float*)d_out;

  char* ws = (char*)d_ws;
  unsigned short* xb   = (unsigned short*)(ws);                                // 16 MB
  unsigned short* wqkv = (unsigned short*)(ws + (size_t)16 * 1024 * 1024);     // 6 MB
  unsigned short* wob  = (unsigned short*)(ws + (size_t)22 * 1024 * 1024);     // 2 MB
  unsigned short* qkv  = (unsigned short*)(ws + (size_t)24 * 1024 * 1024);     // 48 MB
  unsigned short* ob   = (unsigned short*)(ws + (size_t)72 * 1024 * 1024);     // 16 MB

  // converts
  {
    int n4 = 8192 * 1024 / 4;
    k_cvt<<<n4 / 256, 256, 0, stream>>>(x, xb, n4);
    int n4w = 1024 * 1024 / 4;
    k_cvt<<<n4w / 256, 256, 0, stream>>>(wq, wqkv, n4w);
    k_cvt<<<n4w / 256, 256, 0, stream>>>(wk, wqkv + 1024 * 1024, n4w);
    k_cvt<<<n4w / 256, 256, 0, stream>>>(wv, wqkv + 2 * 1024 * 1024, n4w);
    k_cvt<<<n4w / 256, 256, 0, stream>>>(wo, wob, n4w);
  }

  // fused QKV projection: [8192,1024] x [3072,1024]^T -> [8192,3072] bf16
  {
    dim3 g(24, 64);
    k_gemm_nt<0><<<g, 256, 0, stream>>>(xb, wqkv, qkv, 1024, 3072);
  }

  // RoPE on Q and K halves, in place
  k_rope<<<(8192 * 1024) / 256, 256, 0, stream>>>(qkv, pos);

  // causal flash attention -> ob [8192,1024] bf16
  {
    dim3 g(32, 64);
    k_attn<<<g, 256, 0, stream>>>(qkv, ob);
  }

  // output projection: [8192,1024] x [1024,1024]^T -> d_out fp32
  {
    dim3 g(8, 64);
    k_gemm_nt<1><<<g, 256, 0, stream>>>(ob, wob, out, 1024, 1024);
  }
}

// Round 2
// 430.264 us; speedup vs baseline: 1.2329x; 1.2329x over previous
//
#include <hip/hip_runtime.h>
#include <hip/hip_bf16.h>
#include <stdint.h>

#define S_LEN 2048
#define NHEAD 16
#define BATCH 4

typedef __attribute__((ext_vector_type(8))) short short8;
typedef __attribute__((ext_vector_type(4))) float f32x4;
typedef __attribute__((ext_vector_type(4))) unsigned short u16x4;
typedef __attribute__((ext_vector_type(2))) unsigned short u16x2;

__device__ __forceinline__ unsigned short f2bf(float f) {
  union { float f; uint32_t u; } a; a.f = f;
  uint32_t r = (a.u + 0x7fff + ((a.u >> 16) & 1)) >> 16;
  return (unsigned short)r;
}
__device__ __forceinline__ float bf2f(unsigned short u) {
  union { uint32_t u; float f; } a; a.u = ((uint32_t)u) << 16;
  return a.f;
}

__device__ __forceinline__ void gload16(const void* g, void* l) {
  __builtin_amdgcn_global_load_lds(
      (const __attribute__((address_space(1))) void*)g,
      (__attribute__((address_space(3))) void*)l, 16, 0, 0);
}

// ---------------- fp32 -> bf16 convert ----------------
__global__ void k_cvt(const float* __restrict__ src, unsigned short* __restrict__ dst, int n4) {
  int i = blockIdx.x * blockDim.x + threadIdx.x;
  if (i < n4) {
    float4 v = ((const float4*)src)[i];
    u16x4 o;
    o[0] = f2bf(v.x); o[1] = f2bf(v.y); o[2] = f2bf(v.z); o[3] = f2bf(v.w);
    ((u16x4*)dst)[i] = o;
  }
}

// ---------------- NT GEMM: C[M,N] = A[M,K] * B[N,K]^T, bf16 in, fp32 acc ----------------
template<int OUTF32>
__global__ __launch_bounds__(256) void k_gemm_nt(
    const unsigned short* __restrict__ A, const unsigned short* __restrict__ B,
    void* __restrict__ Cp, int K, int ldc)
{
  __shared__ unsigned short lA[128 * 64];
  __shared__ unsigned short lB[128 * 64];
  const int tid = threadIdx.x;
  const int w = tid >> 6, lane = tid & 63;
  const int wm = w >> 1, wn = w & 1;
  const int l15 = lane & 15, lg = lane >> 4;
  const int row0 = blockIdx.y * 128, col0 = blockIdx.x * 128;

  f32x4 acc[4][4] = {};

  const size_t rsb = (size_t)K * 2;  // row stride bytes

  for (int k0 = 0; k0 < K; k0 += 64) {
#pragma unroll
    for (int it = 0; it < 4; ++it) {
      int f = w * 4096 + it * 1024 + lane * 16;
      int r = f >> 7, cb = f & 127;
      gload16((const char*)A + (size_t)(row0 + r) * rsb + k0 * 2 + cb,
              (char*)lA + (w * 4096 + it * 1024));
      gload16((const char*)B + (size_t)(col0 + r) * rsb + k0 * 2 + cb,
              (char*)lB + (w * 4096 + it * 1024));
    }
    __syncthreads();
#pragma unroll
    for (int ks = 0; ks < 2; ++ks) {
      short8 af[4], bg[4];
#pragma unroll
      for (int i = 0; i < 4; ++i) {
        int rowa = wm * 64 + i * 16 + l15;
        af[i] = *(const short8*)((const char*)lA + rowa * 128 + ks * 64 + lg * 16);
        int rowb = wn * 64 + i * 16 + l15;
        bg[i] = *(const short8*)((const char*)lB + rowb * 128 + ks * 64 + lg * 16);
      }
#pragma unroll
      for (int i = 0; i < 4; ++i)
#pragma unroll
        for (int j = 0; j < 4; ++j)
          acc[i][j] = __builtin_amdgcn_mfma_f32_16x16x32_bf16(af[i], bg[j], acc[i][j], 0, 0, 0);
    }
    __syncthreads();
  }

#pragma unroll
  for (int i = 0; i < 4; ++i)
#pragma unroll
    for (int j = 0; j < 4; ++j)
#pragma unroll
      for (int r = 0; r < 4; ++r) {
        int row = row0 + wm * 64 + i * 16 + lg * 4 + r;
        int col = col0 + wn * 64 + j * 16 + l15;
        float v = acc[i][j][r];
        if (OUTF32) ((float*)Cp)[(size_t)row * ldc + col] = v;
        else ((unsigned short*)Cp)[(size_t)row * ldc + col] = f2bf(v);
      }
}

// ---------------- RoPE in-place on fused qkv [8192][3072], cols 0..2047 ----------------
__global__ void k_rope(unsigned short* __restrict__ qkv, const int* __restrict__ pos) {
  int idx = blockIdx.x * 256 + threadIdx.x;
  int row = idx >> 10;
  int c = idx & 1023;
  int which = c >> 9;
  int cp = c & 511;
  int p = cp & 31;
  int s = row & (S_LEN - 1);
  float fp = (float)pos[s];
  float inv = exp2f(-(float)p * 0.41524101186092029f);
  float ang = fp * inv;
  float sn, cs;
  __sincosf(ang, &sn, &cs);
  size_t off = (size_t)row * 3072 + which * 1024 + cp * 2;
  u16x2 v = *(u16x2*)(qkv + off);
  float x0 = bf2f(v[0]), x1 = bf2f(v[1]);
  u16x2 o;
  o[0] = f2bf(cs * x0 - sn * x1);
  o[1] = f2bf(sn * x0 + cs * x1);
  *(u16x2*)(qkv + off) = o;
}

// ---------------- causal flash attention (swapped-QK^T, vectorized V transpose) -------
// grid: (32 qblocks, 64 b*h), block 256. Wave w owns q-rows [qb+w*16, qb+w*16+16).
__global__ __launch_bounds__(256) void k_attn(const unsigned short* __restrict__ qkv,
                                              unsigned short* __restrict__ O) {
  __shared__ unsigned short lK[64 * 64];      // [krow][dk], XOR-swizzled bytes
  __shared__ unsigned short lV[64 * 72];      // transposed [d][kv], kv-pair swizzled
  __shared__ unsigned short lP[4][16 * 72];   // per-wave P [q][k], stride 72

  const int tid = threadIdx.x, w = tid >> 6, lane = tid & 63;
  const int l15 = lane & 15, lg = lane >> 4;
  const int bh = blockIdx.y, b = bh >> 4, h = bh & 15;
  const int qb = ((int)gridDim.x - 1 - (int)blockIdx.x) * 64;

  const size_t rstride = 3072;

  // Q fragments (used as MFMA B-operand): lane l15 = q-row, lg = dk-slice
  short8 qf[2];
  {
    int qrow = qb + w * 16 + l15;
    const unsigned short* qp = qkv + (size_t)(b * S_LEN + qrow) * rstride + h * 64 + lg * 8;
    qf[0] = *(const short8*)qp;
    qf[1] = *(const short8*)(qp + 32);
  }

  // per-lane softmax state for q = l15 (replicated across lg groups), log2 domain
  float mrun = -3e38f, lrun = 0.f;
  f32x4 oacc[4];
#pragma unroll
  for (int j = 0; j < 4; ++j) oacc[j] = (f32x4){0.f, 0.f, 0.f, 0.f};

  const float SCL = 0.18033688011112042f;  // (1/sqrt(64)) * log2(e)

  const int ntiles = (qb >> 6) + 1;
  for (int t = 0; t < ntiles; ++t) {
    const int kv = t * 64;
    __syncthreads();  // previous tile's LDS reads done
    // stage K: linear LDS dest, inverse-swizzled global source
#pragma unroll
    for (int it = 0; it < 2; ++it) {
      int f = w * 2048 + it * 1024 + lane * 16;
      int r = f >> 7;
      int cb = (f ^ ((r & 7) << 4)) & 127;
      gload16((const char*)qkv + ((size_t)(b * S_LEN + kv + r) * rstride + 1024 + h * 64) * 2 + cb,
              (char*)lK + (w * 2048 + it * 1024));
    }
    // stage V transposed [d][kv] with lane-pair exchange, packed b32 writes
#pragma unroll
    for (int it = 0; it < 2; ++it) {
      int gid = it * 256 + tid;            // 0..511
      int kp = gid >> 4;                   // kv pair 0..31
      int sub = gid & 15;
      int p = sub & 1;
      int c = (sub >> 1) * 8;              // d base 0..56
      const unsigned short* src = qkv + (size_t)(b * S_LEN + kv + kp * 2 + p) * rstride + 2048 + h * 64 + c;
      short8 vv = *(const short8*)src;
      uint32_t u0 = __shfl_xor(((const uint32_t*)&vv)[0], 1);
      uint32_t u1 = __shfl_xor(((const uint32_t*)&vv)[1], 1);
      uint32_t u2 = __shfl_xor(((const uint32_t*)&vv)[2], 1);
      uint32_t u3 = __shfl_xor(((const uint32_t*)&vv)[3], 1);
      unsigned short ov[8];
      ((uint32_t*)ov)[0] = u0; ((uint32_t*)ov)[1] = u1;
      ((uint32_t*)ov)[2] = u2; ((uint32_t*)ov)[3] = u3;
      const unsigned short* own = (const unsigned short*)&vv;
#pragma unroll
      for (int j = 0; j < 4; ++j) {
        int d = c + (p ? 4 : 0) + j;
        unsigned short lo = p ? ov[4 + j] : own[j];
        unsigned short hi = p ? own[4 + j] : ov[j];
        uint32_t packed = (uint32_t)lo | ((uint32_t)hi << 16);
        int kps = kp ^ (((d >> 2) & 7) << 2);
        ((uint32_t*)lV)[d * 36 + kps] = packed;
      }
    }
    __syncthreads();  // K landed (vmcnt drained at barrier), V writes visible

    // QK^T swapped: S^T[k][q] = mfma(A=K, B=Q). lane: col q = l15, rows k = lg*4+r (+16*jf)
    f32x4 sf[4] = {};
    __builtin_amdgcn_s_setprio(1);
#pragma unroll
    for (int ks = 0; ks < 2; ++ks) {
#pragma unroll
      for (int jf = 0; jf < 4; ++jf) {
        int krow = jf * 16 + l15;
        int g = krow * 128 + ks * 64 + lg * 16;
        int a = g ^ ((krow & 7) << 4);
        short8 kb = *(const short8*)((const char*)lK + a);
        sf[jf] = __builtin_amdgcn_mfma_f32_16x16x32_bf16(kb, qf[ks], sf[jf], 0, 0, 0);
      }
    }
    __builtin_amdgcn_s_setprio(0);

    // online softmax, per-lane row q = l15, values k = jf*16 + lg*4 + r (log2 domain)
    const bool diag = (kv == qb);
    const int qglob = qb + w * 16 + l15;
    float pv[4][4];
    float mx = -3e38f;
#pragma unroll
    for (int jf = 0; jf < 4; ++jf)
#pragma unroll
      for (int r = 0; r < 4; ++r) {
        float v = sf[jf][r] * SCL;
        if (diag) {
          int kglob = kv + jf * 16 + lg * 4 + r;
          if (kglob > qglob) v = -3e38f;
        }
        pv[jf][r] = v;
        mx = fmaxf(mx, v);
      }
    mx = fmaxf(mx, __shfl_xor(mx, 16));
    mx = fmaxf(mx, __shfl_xor(mx, 32));
    float mn = fmaxf(mrun, mx);
    float alpha = exp2f(mrun - mn);
    mrun = mn;
    float ps = 0.f;
#pragma unroll
    for (int jf = 0; jf < 4; ++jf)
#pragma unroll
      for (int r = 0; r < 4; ++r) {
        float e = exp2f(pv[jf][r] - mn);
        pv[jf][r] = e;
        ps += e;
      }
    ps += __shfl_xor(ps, 16);
    ps += __shfl_xor(ps, 32);
    lrun = lrun * alpha + ps;

    // rescale O accumulator: row q = lg*4 + r needs alpha from lane l15 = lg*4+r
    float ar[4];
#pragma unroll
    for (int r = 0; r < 4; ++r) ar[r] = __shfl(alpha, lg * 4 + r, 16);
#pragma unroll
    for (int j = 0; j < 4; ++j)
#pragma unroll
      for (int r = 0; r < 4; ++r)
        oacc[j][r] *= ar[r];

    // write P to per-wave LDS [q=l15][k], packed b64 along r
    unsigned short* pw = &lP[w][0];
#pragma unroll
    for (int jf = 0; jf < 4; ++jf) {
      u16x4 pk;
#pragma unroll
      for (int r = 0; r < 4; ++r) pk[r] = f2bf(pv[jf][r]);
      *(u16x4*)(pw + l15 * 72 + jf * 16 + lg * 4) = pk;
    }

    // PV: O[q][d] += P[q][k] * V[k][d]
    __builtin_amdgcn_s_setprio(1);
#pragma unroll
    for (int ks = 0; ks < 2; ++ks) {
      short8 pa = *(const short8*)(pw + l15 * 72 + ks * 32 + lg * 8);
      int B = ks * 16 + lg * 4;  // kv dword base
#pragma unroll
      for (int j = 0; j < 4; ++j) {
        int d = j * 16 + l15;
        int f = ((d >> 2) & 7) << 2;
        short8 vb = *(const short8*)((const char*)lV + d * 144 + 4 * (B ^ f));
        oacc[j] = __builtin_amdgcn_mfma_f32_16x16x32_bf16(pa, vb, oacc[j], 0, 0, 0);
      }
    }
    __builtin_amdgcn_s_setprio(0);
  }

  // write O (bf16) [8192][1024]; need l for q-row lg*4+r from lane l15=lg*4+r
  float lrow[4];
#pragma unroll
  for (int r = 0; r < 4; ++r) lrow[r] = __shfl(lrun, lg * 4 + r, 16);
#pragma unroll
  for (int j = 0; j < 4; ++j)
#pragma unroll
    for (int r = 0; r < 4; ++r) {
      int qrow = qb + w * 16 + lg * 4 + r;
      float v = oacc[j][r] / lrow[r];
      O[(size_t)(b * S_LEN + qrow) * 1024 + h * 64 + j * 16 + l15] = f2bf(v);
    }
}

extern "C" void kernel_launch(void* const* d_in, const int* in_sizes, int n_in,
                              void* d_out, int out_size, void* d_ws, size_t ws_size,
                              hipStream_t stream) {
  const float* x  = (const float*)d_in[0];
  const int* pos  = (const int*)d_in[1];
  const float* wq = (const float*)d_in[2];
  const float* wk = (const float*)d_in[3];
  const float* wv = (const float*)d_in[4];
  const float* wo = (const float*)d_in[5];
  float* out = (float*)d_out;

  char* ws = (char*)d_ws;
  unsigned short* xb   = (unsigned short*)(ws);
  unsigned short* wqkv = (unsigned short*)(ws + (size_t)16 * 1024 * 1024);
  unsigned short* wob  = (unsigned short*)(ws + (size_t)22 * 1024 * 1024);
  unsigned short* qkv  = (unsigned short*)(ws + (size_t)24 * 1024 * 1024);
  unsigned short* ob   = (unsigned short*)(ws + (size_t)72 * 1024 * 1024);

  {
    int n4 = 8192 * 1024 / 4;
    k_cvt<<<n4 / 256, 256, 0, stream>>>(x, xb, n4);
    int n4w = 1024 * 1024 / 4;
    k_cvt<<<n4w / 256, 256, 0, stream>>>(wq, wqkv, n4w);
    k_cvt<<<n4w / 256, 256, 0, stream>>>(wk, wqkv + 1024 * 1024, n4w);
    k_cvt<<<n4w / 256, 256, 0, stream>>>(wv, wqkv + 2 * 1024 * 1024, n4w);
    k_cvt<<<n4w / 256, 256, 0, stream>>>(wo, wob, n4w);
  }

  {
    dim3 g(24, 64);
    k_gemm_nt<0><<<g, 256, 0, stream>>>(xb, wqkv, qkv, 1024, 3072);
  }

  k_rope<<<(8192 * 1024) / 256, 256, 0, stream>>>(qkv, pos);

  {
    dim3 g(32, 64);
    k_attn<<<g, 256, 0, stream>>>(qkv, ob);
  }

  {
    dim3 g(8, 64);
    k_gemm_nt<1><<<g, 256, 0, stream>>>(ob, wob, out, 1024, 1024);
  }
}

// Round 3
// 422.948 us; speedup vs baseline: 1.2542x; 1.0173x over previous
//
#include <hip/hip_runtime.h>
#include <hip/hip_bf16.h>
#include <stdint.h>

#define S_LEN 2048
#define NHEAD 16
#define BATCH 4

typedef __attribute__((ext_vector_type(8))) short short8;
typedef __attribute__((ext_vector_type(4))) float f32x4;
typedef __attribute__((ext_vector_type(4))) unsigned short u16x4;
typedef __attribute__((ext_vector_type(2))) unsigned short u16x2;

__device__ __forceinline__ unsigned short f2bf(float f) {
  union { float f; uint32_t u; } a; a.f = f;
  uint32_t r = (a.u + 0x7fff + ((a.u >> 16) & 1)) >> 16;
  return (unsigned short)r;
}
__device__ __forceinline__ float bf2f(unsigned short u) {
  union { uint32_t u; float f; } a; a.u = ((uint32_t)u) << 16;
  return a.f;
}
// packed pair convert: compiler emits v_cvt_pk_bf16_f32
__device__ __forceinline__ uint32_t pk2bf(float a, float b) {
  union { __hip_bfloat162 h; uint32_t u; } cv;
  cv.h = __float22bfloat162_rn(float2{a, b});
  return cv.u;
}

__device__ __forceinline__ void gload16(const void* g, void* l) {
  __builtin_amdgcn_global_load_lds(
      (const __attribute__((address_space(1))) void*)g,
      (__attribute__((address_space(3))) void*)l, 16, 0, 0);
}

// ---------------- fp32 -> bf16 convert ----------------
__global__ void k_cvt(const float* __restrict__ src, unsigned short* __restrict__ dst, int n4) {
  int i = blockIdx.x * blockDim.x + threadIdx.x;
  if (i < n4) {
    float4 v = ((const float4*)src)[i];
    union { uint32_t u[2]; u16x4 v; } o;
    o.u[0] = pk2bf(v.x, v.y);
    o.u[1] = pk2bf(v.z, v.w);
    ((u16x4*)dst)[i] = o.v;
  }
}

// all 4 weight matrices in one launch; dst regions contiguous (wq,wk,wv,wo)
__global__ void k_cvt4(const float* __restrict__ s0, const float* __restrict__ s1,
                       const float* __restrict__ s2, const float* __restrict__ s3,
                       unsigned short* __restrict__ dst) {
  int i = blockIdx.x * 256 + threadIdx.x;     // 1M quads total
  int r = i >> 18;                            // 256K quads per matrix
  const float* s = r == 0 ? s0 : r == 1 ? s1 : r == 2 ? s2 : s3;
  float4 v = ((const float4*)s)[i & 0x3FFFF];
  union { uint32_t u[2]; u16x4 v; } o;
  o.u[0] = pk2bf(v.x, v.y);
  o.u[1] = pk2bf(v.z, v.w);
  ((u16x4*)dst)[i] = o.v;
}

// ---------------- NT GEMM: C[M,N] = A[M,K] * B[N,K]^T, bf16 in, fp32 acc ----------------
template<int OUTF32>
__global__ __launch_bounds__(256) void k_gemm_nt(
    const unsigned short* __restrict__ A, const unsigned short* __restrict__ B,
    void* __restrict__ Cp, int K, int ldc)
{
  __shared__ unsigned short lA[128 * 64];
  __shared__ unsigned short lB[128 * 64];
  const int tid = threadIdx.x;
  const int w = tid >> 6, lane = tid & 63;
  const int wm = w >> 1, wn = w & 1;
  const int l15 = lane & 15, lg = lane >> 4;
  const int row0 = blockIdx.y * 128, col0 = blockIdx.x * 128;

  f32x4 acc[4][4] = {};
  const size_t rsb = (size_t)K * 2;

  for (int k0 = 0; k0 < K; k0 += 64) {
#pragma unroll
    for (int it = 0; it < 4; ++it) {
      int f = w * 4096 + it * 1024 + lane * 16;
      int r = f >> 7, cb = f & 127;
      gload16((const char*)A + (size_t)(row0 + r) * rsb + k0 * 2 + cb,
              (char*)lA + (w * 4096 + it * 1024));
      gload16((const char*)B + (size_t)(col0 + r) * rsb + k0 * 2 + cb,
              (char*)lB + (w * 4096 + it * 1024));
    }
    __syncthreads();
#pragma unroll
    for (int ks = 0; ks < 2; ++ks) {
      short8 af[4], bg[4];
#pragma unroll
      for (int i = 0; i < 4; ++i) {
        int rowa = wm * 64 + i * 16 + l15;
        af[i] = *(const short8*)((const char*)lA + rowa * 128 + ks * 64 + lg * 16);
        int rowb = wn * 64 + i * 16 + l15;
        bg[i] = *(const short8*)((const char*)lB + rowb * 128 + ks * 64 + lg * 16);
      }
#pragma unroll
      for (int i = 0; i < 4; ++i)
#pragma unroll
        for (int j = 0; j < 4; ++j)
          acc[i][j] = __builtin_amdgcn_mfma_f32_16x16x32_bf16(af[i], bg[j], acc[i][j], 0, 0, 0);
    }
    __syncthreads();
  }

#pragma unroll
  for (int i = 0; i < 4; ++i)
#pragma unroll
    for (int j = 0; j < 4; ++j)
#pragma unroll
      for (int r = 0; r < 4; ++r) {
        int row = row0 + wm * 64 + i * 16 + lg * 4 + r;
        int col = col0 + wn * 64 + j * 16 + l15;
        float v = acc[i][j][r];
        if (OUTF32) ((float*)Cp)[(size_t)row * ldc + col] = v;
        else ((unsigned short*)Cp)[(size_t)row * ldc + col] = f2bf(v);
      }
}

// ---------------- RoPE: cos/sin table then table-driven rotate ----------------
__global__ void k_tab(const int* __restrict__ pos, float* __restrict__ tab) {
  int i = blockIdx.x * 256 + threadIdx.x;  // 65536 = s*32 + p
  int s = i >> 5, p = i & 31;
  float fp = (float)pos[s];
  float inv = exp2f(-(float)p * 0.41524101186092029f);
  float ang = fp * inv;
  float sn, cs;
  __sincosf(ang, &sn, &cs);
  ((float2*)tab)[i] = float2{cs, sn};
}

__global__ void k_rope(unsigned short* __restrict__ qkv, const float* __restrict__ tab) {
  int idx = blockIdx.x * 256 + threadIdx.x;  // 2M threads, 4 pairs each
  int row = idx >> 8;
  int rem = idx & 255;
  int which = rem >> 7;       // 0=Q cols, 1=K cols
  int cq = rem & 127;         // quad-of-pairs index
  int p0 = (cq * 4) & 31;     // pair within head (aligned quad)
  int s = row & (S_LEN - 1);
  const float4* tb = (const float4*)(tab + (size_t)(s * 32 + p0) * 2);
  float4 t0 = tb[0], t1 = tb[1];
  size_t off = (size_t)row * 3072 + which * 1024 + cq * 8;
  short8 v = *(short8*)(qkv + off);
  float x0 = bf2f((unsigned short)v[0]), x1 = bf2f((unsigned short)v[1]);
  float x2 = bf2f((unsigned short)v[2]), x3 = bf2f((unsigned short)v[3]);
  float x4 = bf2f((unsigned short)v[4]), x5 = bf2f((unsigned short)v[5]);
  float x6 = bf2f((unsigned short)v[6]), x7 = bf2f((unsigned short)v[7]);
  union { uint32_t u[4]; short8 v; } o;
  o.u[0] = pk2bf(t0.x * x0 - t0.y * x1, t0.y * x0 + t0.x * x1);
  o.u[1] = pk2bf(t0.z * x2 - t0.w * x3, t0.w * x2 + t0.z * x3);
  o.u[2] = pk2bf(t1.x * x4 - t1.y * x5, t1.y * x4 + t1.x * x5);
  o.u[3] = pk2bf(t1.z * x6 - t1.w * x7, t1.w * x6 + t1.z * x7);
  *(short8*)(qkv + off) = o.v;
}

// ---------------- causal flash attention, double-buffered prefetch pipeline -------
// grid: (32 qblocks, 64 b*h), block 256. Wave w owns q-rows [qb+w*16, qb+w*16+16).
__global__ __launch_bounds__(256) void k_attn(const unsigned short* __restrict__ qkv,
                                              unsigned short* __restrict__ O) {
  __shared__ unsigned short lK[2][64 * 64];   // [krow][dk], XOR-swizzled bytes
  __shared__ unsigned short lV[2][64 * 72];   // transposed [d][kv], kv-pair swizzled
  __shared__ unsigned short lP[4][16 * 72];   // per-wave P [q][k]

  const int tid = threadIdx.x, w = tid >> 6, lane = tid & 63;
  const int l15 = lane & 15, lg = lane >> 4;
  const int bh = blockIdx.y, b = bh >> 4, h = bh & 15;
  const int qb = ((int)gridDim.x - 1 - (int)blockIdx.x) * 64;
  const size_t rstride = 3072;

  short8 qf[2];
  {
    int qrow = qb + w * 16 + l15;
    const unsigned short* qp = qkv + (size_t)(b * S_LEN + qrow) * rstride + h * 64 + lg * 8;
    qf[0] = *(const short8*)qp;
    qf[1] = *(const short8*)(qp + 32);
  }

  float mrun = -3e38f, lrun = 0.f;
  f32x4 oacc[4] = {};
  const float SCL = 0.18033688011112042f;  // (1/sqrt(64)) * log2(e)
  const int ntiles = (qb >> 6) + 1;

  short8 vr0, vr1;  // V tile staged in regs (issue-early / write-late)

  auto stageK = [&](int buf, int t) {
#pragma unroll
    for (int it = 0; it < 2; ++it) {
      int f = w * 2048 + it * 1024 + lane * 16;
      int r = f >> 7;
      int cb = (f ^ ((r & 7) << 4)) & 127;
      gload16((const char*)qkv + ((size_t)(b * S_LEN + t * 64 + r) * rstride + 1024 + h * 64) * 2 + cb,
              (char*)(&lK[buf][0]) + (w * 2048 + it * 1024));
    }
  };
  auto loadV = [&](int t) {
#pragma unroll
    for (int it = 0; it < 2; ++it) {
      int gid = it * 256 + tid;
      int kp = gid >> 4, sub = gid & 15;
      int p = sub & 1, c = (sub >> 1) * 8;
      const unsigned short* src =
          qkv + (size_t)(b * S_LEN + t * 64 + kp * 2 + p) * rstride + 2048 + h * 64 + c;
      short8 vv = *(const short8*)src;
      if (it == 0) vr0 = vv; else vr1 = vv;
    }
  };
  auto writeV = [&](int buf) {
#pragma unroll
    for (int it = 0; it < 2; ++it) {
      int gid = it * 256 + tid;
      int kp = gid >> 4, sub = gid & 15;
      int p = sub & 1, c = (sub >> 1) * 8;
      short8 vv = (it == 0) ? vr0 : vr1;
      uint32_t u0 = __shfl_xor(((const uint32_t*)&vv)[0], 1);
      uint32_t u1 = __shfl_xor(((const uint32_t*)&vv)[1], 1);
      uint32_t u2 = __shfl_xor(((const uint32_t*)&vv)[2], 1);
      uint32_t u3 = __shfl_xor(((const uint32_t*)&vv)[3], 1);
      unsigned short ov[8];
      ((uint32_t*)ov)[0] = u0; ((uint32_t*)ov)[1] = u1;
      ((uint32_t*)ov)[2] = u2; ((uint32_t*)ov)[3] = u3;
      const unsigned short* own = (const unsigned short*)&vv;
#pragma unroll
      for (int j = 0; j < 4; ++j) {
        int d = c + (p ? 4 : 0) + j;
        unsigned short lo = p ? ov[4 + j] : own[j];
        unsigned short hi = p ? own[4 + j] : ov[j];
        uint32_t packed = (uint32_t)lo | ((uint32_t)hi << 16);
        int kps = kp ^ (((d >> 2) & 7) << 2);
        ((uint32_t*)(&lV[buf][0]))[d * 36 + kps] = packed;
      }
    }
  };

  // prologue: stage tile 0
  stageK(0, 0);
  loadV(0);
  writeV(0);
  __syncthreads();

  for (int t = 0; t < ntiles; ++t) {
    const int cur = t & 1, nxt = cur ^ 1;
    const bool more = (t + 1 < ntiles);
    if (more) { stageK(nxt, t + 1); loadV(t + 1); }  // issue-early

    // QK^T swapped: mfma(A=K, B=Q) -> lane holds q=l15, k = jf*16+lg*4+r
    f32x4 sf[4] = {};
    __builtin_amdgcn_s_setprio(1);
#pragma unroll
    for (int ks = 0; ks < 2; ++ks) {
#pragma unroll
      for (int jf = 0; jf < 4; ++jf) {
        int krow = jf * 16 + l15;
        int g = krow * 128 + ks * 64 + lg * 16;
        int a = g ^ ((krow & 7) << 4);
        short8 kb = *(const short8*)((const char*)(&lK[cur][0]) + a);
        sf[jf] = __builtin_amdgcn_mfma_f32_16x16x32_bf16(kb, qf[ks], sf[jf], 0, 0, 0);
      }
    }
    __builtin_amdgcn_s_setprio(0);

    // online softmax (log2 domain), defer-max (T13)
    const int kv = t * 64;
    const bool diag = (kv == qb);
    const int qglob = qb + w * 16 + l15;
    float pv[4][4];
    float mx = -3e38f;
#pragma unroll
    for (int jf = 0; jf < 4; ++jf)
#pragma unroll
      for (int r = 0; r < 4; ++r) {
        float v = sf[jf][r] * SCL;
        if (diag) {
          int kglob = kv + jf * 16 + lg * 4 + r;
          if (kglob > qglob) v = -3e38f;
        }
        pv[jf][r] = v;
        mx = fmaxf(mx, v);
      }
    mx = fmaxf(mx, __shfl_xor(mx, 16));
    mx = fmaxf(mx, __shfl_xor(mx, 32));
    if (!__all(mx - mrun <= 8.0f)) {
      float mn = fmaxf(mrun, mx);
      float alpha = exp2f(mrun - mn);
      mrun = mn;
      float ar[4];
#pragma unroll
      for (int r = 0; r < 4; ++r) ar[r] = __shfl(alpha, lg * 4 + r, 16);
#pragma unroll
      for (int j = 0; j < 4; ++j)
#pragma unroll
        for (int r = 0; r < 4; ++r)
          oacc[j][r] *= ar[r];
      lrun *= alpha;
    }
    float ps = 0.f;
#pragma unroll
    for (int jf = 0; jf < 4; ++jf)
#pragma unroll
      for (int r = 0; r < 4; ++r) {
        float e = exp2f(pv[jf][r] - mrun);
        pv[jf][r] = e;
        ps += e;
      }
    ps += __shfl_xor(ps, 16);
    ps += __shfl_xor(ps, 32);
    lrun += ps;

    // P -> per-wave LDS (packed cvt_pk writes)
    unsigned short* pw = &lP[w][0];
#pragma unroll
    for (int jf = 0; jf < 4; ++jf) {
      union { uint32_t u[2]; u16x4 v; } pk;
      pk.u[0] = pk2bf(pv[jf][0], pv[jf][1]);
      pk.u[1] = pk2bf(pv[jf][2], pv[jf][3]);
      *(u16x4*)(pw + l15 * 72 + jf * 16 + lg * 4) = pk.v;
    }

    // PV
    __builtin_amdgcn_s_setprio(1);
#pragma unroll
    for (int ks = 0; ks < 2; ++ks) {
      short8 pa = *(const short8*)(pw + l15 * 72 + ks * 32 + lg * 8);
      int B = ks * 16 + lg * 4;
#pragma unroll
      for (int j = 0; j < 4; ++j) {
        int d = j * 16 + l15;
        int f = ((d >> 2) & 7) << 2;
        short8 vb = *(const short8*)((const char*)(&lV[cur][0]) + d * 144 + 4 * (B ^ f));
        oacc[j] = __builtin_amdgcn_mfma_f32_16x16x32_bf16(pa, vb, oacc[j], 0, 0, 0);
      }
    }
    __builtin_amdgcn_s_setprio(0);

    if (more) writeV(nxt);   // write-late: vmcnt wait for vr hidden under compute
    __syncthreads();         // drains K gload_lds (vmcnt) + V ds_writes (lgkm)
  }

  // O write
  float lrow[4];
#pragma unroll
  for (int r = 0; r < 4; ++r) lrow[r] = __shfl(lrun, lg * 4 + r, 16);
#pragma unroll
  for (int j = 0; j < 4; ++j)
#pragma unroll
    for (int r = 0; r < 4; ++r) {
      int qrow = qb + w * 16 + lg * 4 + r;
      float v = oacc[j][r] / lrow[r];
      O[(size_t)(b * S_LEN + qrow) * 1024 + h * 64 + j * 16 + l15] = f2bf(v);
    }
}

extern "C" void kernel_launch(void* const* d_in, const int* in_sizes, int n_in,
                              void* d_out, int out_size, void* d_ws, size_t ws_size,
                              hipStream_t stream) {
  const float* x  = (const float*)d_in[0];
  const int* pos  = (const int*)d_in[1];
  const float* wq = (const float*)d_in[2];
  const float* wk = (const float*)d_in[3];
  const float* wv = (const float*)d_in[4];
  const float* wo = (const float*)d_in[5];
  float* out = (float*)d_out;

  char* ws = (char*)d_ws;
  unsigned short* xb   = (unsigned short*)(ws);                              // 16 MB
  unsigned short* wqkv = (unsigned short*)(ws + (size_t)16 * 1024 * 1024);   // 6 MB
  unsigned short* wob  = (unsigned short*)(ws + (size_t)22 * 1024 * 1024);   // 2 MB (contig after wqkv)
  unsigned short* qkv  = (unsigned short*)(ws + (size_t)24 * 1024 * 1024);   // 48 MB
  unsigned short* ob   = (unsigned short*)(ws + (size_t)72 * 1024 * 1024);   // 16 MB
  float* tab = (float*)xb;  // reuse xb region after gemm1 consumed it (512 KB)

  // converts
  k_cvt<<<8192, 256, 0, stream>>>(x, xb, 8192 * 1024 / 4);
  k_cvt4<<<4096, 256, 0, stream>>>(wq, wk, wv, wo, wqkv);

  // fused QKV projection: [8192,1024] x [3072,1024]^T -> [8192,3072] bf16
  {
    dim3 g(24, 64);
    k_gemm_nt<0><<<g, 256, 0, stream>>>(xb, wqkv, qkv, 1024, 3072);
  }

  // RoPE table (into xb region — gemm1 is done with it) + apply
  k_tab<<<256, 256, 0, stream>>>(pos, tab);
  k_rope<<<8192, 256, 0, stream>>>(qkv, tab);

  // causal flash attention -> ob [8192,1024] bf16
  {
    dim3 g(32, 64);
    k_attn<<<g, 256, 0, stream>>>(qkv, ob);
  }

  // output projection: [8192,1024] x [1024,1024]^T -> d_out fp32
  {
    dim3 g(8, 64);
    k_gemm_nt<1><<<g, 256, 0, stream>>>(ob, wob, out, 1024, 1024);
  }
}

// Round 6
// 363.954 us; speedup vs baseline: 1.4575x; 1.1621x over previous
//
#include <hip/hip_runtime.h>
#include <hip/hip_bf16.h>
#include <stdint.h>

#define S_LEN 2048
#define NHEAD 16
#define BATCH 4

typedef __attribute__((ext_vector_type(8))) short short8;
typedef __attribute__((ext_vector_type(4))) float f32x4;
typedef __attribute__((ext_vector_type(4))) unsigned short u16x4;
typedef __attribute__((ext_vector_type(2))) unsigned short u16x2;

__device__ __forceinline__ unsigned short f2bf(float f) {
  union { float f; uint32_t u; } a; a.f = f;
  uint32_t r = (a.u + 0x7fff + ((a.u >> 16) & 1)) >> 16;
  return (unsigned short)r;
}
__device__ __forceinline__ float bf2f(unsigned short u) {
  union { uint32_t u; float f; } a; a.u = ((uint32_t)u) << 16;
  return a.f;
}
__device__ __forceinline__ uint32_t pk2bf(float a, float b) {
  union { __hip_bfloat162 h; uint32_t u; } cv;
  cv.h = __float22bfloat162_rn(float2{a, b});
  return cv.u;
}

__device__ __forceinline__ void gload16(const void* g, void* l) {
  __builtin_amdgcn_global_load_lds(
      (const __attribute__((address_space(1))) void*)g,
      (__attribute__((address_space(3))) void*)l, 16, 0, 0);
}

// ---------------- fp32 -> bf16 convert ----------------
__global__ void k_cvt(const float* __restrict__ src, unsigned short* __restrict__ dst, int n4) {
  int i = blockIdx.x * blockDim.x + threadIdx.x;
  if (i < n4) {
    float4 v = ((const float4*)src)[i];
    union { uint32_t u[2]; u16x4 v; } o;
    o.u[0] = pk2bf(v.x, v.y);
    o.u[1] = pk2bf(v.z, v.w);
    ((u16x4*)dst)[i] = o.v;
  }
}

__global__ void k_cvt4(const float* __restrict__ s0, const float* __restrict__ s1,
                       const float* __restrict__ s2, const float* __restrict__ s3,
                       unsigned short* __restrict__ dst) {
  int i = blockIdx.x * 256 + threadIdx.x;
  int r = i >> 18;
  const float* s = r == 0 ? s0 : r == 1 ? s1 : r == 2 ? s2 : s3;
  float4 v = ((const float4*)s)[i & 0x3FFFF];
  union { uint32_t u[2]; u16x4 v; } o;
  o.u[0] = pk2bf(v.x, v.y);
  o.u[1] = pk2bf(v.z, v.w);
  ((u16x4*)dst)[i] = o.v;
}

// ---------------- NT GEMM: C[M,N] = A[M,K] * B[N,K]^T, XCD-swizzled 1D grid ----------
template<int OUTF32>
__global__ __launch_bounds__(256) void k_gemm_nt(
    const unsigned short* __restrict__ A, const unsigned short* __restrict__ B,
    void* __restrict__ Cp, int K, int ldc, int gx)
{
  __shared__ unsigned short lA[128 * 64];
  __shared__ unsigned short lB[128 * 64];
  const int tid = threadIdx.x;
  const int w = tid >> 6, lane = tid & 63;
  const int wm = w >> 1, wn = w & 1;
  const int l15 = lane & 15, lg = lane >> 4;
  const int nwg = (int)gridDim.x, slot = (int)blockIdx.x;
  const int f = (slot & 7) * (nwg >> 3) + (slot >> 3);   // XCD k gets contiguous chunk
  const int row0 = (f / gx) * 128, col0 = (f % gx) * 128;

  f32x4 acc[4][4] = {};
  const size_t rsb = (size_t)K * 2;

  for (int k0 = 0; k0 < K; k0 += 64) {
#pragma unroll
    for (int it = 0; it < 4; ++it) {
      int fb = w * 4096 + it * 1024 + lane * 16;
      int r = fb >> 7, cb = fb & 127;
      gload16((const char*)A + (size_t)(row0 + r) * rsb + k0 * 2 + cb,
              (char*)lA + (w * 4096 + it * 1024));
      gload16((const char*)B + (size_t)(col0 + r) * rsb + k0 * 2 + cb,
              (char*)lB + (w * 4096 + it * 1024));
    }
    __syncthreads();
#pragma unroll
    for (int ks = 0; ks < 2; ++ks) {
      short8 af[4], bg[4];
#pragma unroll
      for (int i = 0; i < 4; ++i) {
        int rowa = wm * 64 + i * 16 + l15;
        af[i] = *(const short8*)((const char*)lA + rowa * 128 + ks * 64 + lg * 16);
        int rowb = wn * 64 + i * 16 + l15;
        bg[i] = *(const short8*)((const char*)lB + rowb * 128 + ks * 64 + lg * 16);
      }
#pragma unroll
      for (int i = 0; i < 4; ++i)
#pragma unroll
        for (int j = 0; j < 4; ++j)
          acc[i][j] = __builtin_amdgcn_mfma_f32_16x16x32_bf16(af[i], bg[j], acc[i][j], 0, 0, 0);
    }
    __syncthreads();
  }

#pragma unroll
  for (int i = 0; i < 4; ++i)
#pragma unroll
    for (int j = 0; j < 4; ++j)
#pragma unroll
      for (int r = 0; r < 4; ++r) {
        int row = row0 + wm * 64 + i * 16 + lg * 4 + r;
        int col = col0 + wn * 64 + j * 16 + l15;
        float v = acc[i][j][r];
        if (OUTF32) ((float*)Cp)[(size_t)row * ldc + col] = v;
        else ((unsigned short*)Cp)[(size_t)row * ldc + col] = f2bf(v);
      }
}

// ---------------- RoPE table + apply ----------------
__global__ void k_tab(const int* __restrict__ pos, float* __restrict__ tab) {
  int i = blockIdx.x * 256 + threadIdx.x;
  int s = i >> 5, p = i & 31;
  float fp = (float)pos[s];
  float inv = exp2f(-(float)p * 0.41524101186092029f);
  float ang = fp * inv;
  float sn, cs;
  __sincosf(ang, &sn, &cs);
  ((float2*)tab)[i] = float2{cs, sn};
}

__global__ void k_rope(unsigned short* __restrict__ qkv, const float* __restrict__ tab) {
  int idx = blockIdx.x * 256 + threadIdx.x;
  int row = idx >> 8;
  int rem = idx & 255;
  int which = rem >> 7;
  int cq = rem & 127;
  int p0 = (cq * 4) & 31;
  int s = row & (S_LEN - 1);
  const float4* tb = (const float4*)(tab + (size_t)(s * 32 + p0) * 2);
  float4 t0 = tb[0], t1 = tb[1];
  size_t off = (size_t)row * 3072 + which * 1024 + cq * 8;
  short8 v = *(short8*)(qkv + off);
  float x0 = bf2f((unsigned short)v[0]), x1 = bf2f((unsigned short)v[1]);
  float x2 = bf2f((unsigned short)v[2]), x3 = bf2f((unsigned short)v[3]);
  float x4 = bf2f((unsigned short)v[4]), x5 = bf2f((unsigned short)v[5]);
  float x6 = bf2f((unsigned short)v[6]), x7 = bf2f((unsigned short)v[7]);
  union { uint32_t u[4]; short8 v; } o;
  o.u[0] = pk2bf(t0.x * x0 - t0.y * x1, t0.y * x0 + t0.x * x1);
  o.u[1] = pk2bf(t0.z * x2 - t0.w * x3, t0.w * x2 + t0.z * x3);
  o.u[2] = pk2bf(t1.x * x4 - t1.y * x5, t1.y * x4 + t1.x * x5);
  o.u[3] = pk2bf(t1.z * x6 - t1.w * x7, t1.w * x6 + t1.z * x7);
  *(short8*)(qkv + off) = o.v;
}

// ---------------- causal flash attention: 8 waves, QBLK=128, XCD-swizzled -----------
// 1024 blocks of 512 threads. Wave w owns q-rows [qb+w*16, qb+w*16+16).
__global__ __launch_bounds__(512) void k_attn(const unsigned short* __restrict__ qkv,
                                              unsigned short* __restrict__ O) {
  __shared__ unsigned short lK[2][64 * 64];   // [krow][dk], XOR-swizzled bytes
  __shared__ unsigned short lV[2][64 * 72];   // transposed [d][kv], kv-pair swizzled
  __shared__ unsigned short lP[8][16 * 72];   // per-wave P [q][k]

  const int tid = threadIdx.x, w = tid >> 6, lane = tid & 63;
  const int l15 = lane & 15, lg = lane >> 4;
  // XCD swizzle: XCD k (slot%8) gets bh in [8k, 8k+8), all 16 q-blocks each
  const int slot = (int)blockIdx.x;
  const int f0 = (slot & 7) * 128 + (slot >> 3);
  const int bh = f0 >> 4, qx = f0 & 15;
  const int b = bh >> 4, h = bh & 15;
  const int qb = (15 - qx) * 128;               // big blocks dispatch first
  const size_t rstride = 3072;

  short8 qf[2];
  {
    int qrow = qb + w * 16 + l15;
    const unsigned short* qp = qkv + (size_t)(b * S_LEN + qrow) * rstride + h * 64 + lg * 8;
    qf[0] = *(const short8*)qp;
    qf[1] = *(const short8*)(qp + 32);
  }

  float mrun = -3e38f, lrun = 0.f;
  f32x4 oacc[4] = {};
  const float SCL = 0.18033688011112042f;  // (1/sqrt(64)) * log2(e)
  const int ntiles = (qb >> 6) + 2;

  short8 vr;  // V tile staged in regs (issue-early / write-late)

  auto stageK = [&](int buf, int t) {
    int fb = tid * 16;                       // 512 threads x 16B = 8KB tile
    int r = fb >> 7;
    int cb = (fb ^ ((r & 7) << 4)) & 127;
    gload16((const char*)qkv + ((size_t)(b * S_LEN + t * 64 + r) * rstride + 1024 + h * 64) * 2 + cb,
            (char*)(&lK[buf][0]) + fb);
  };
  auto loadV = [&](int t) {
    int kp = tid >> 4, sub = tid & 15;
    int p = sub & 1, c = (sub >> 1) * 8;
    vr = *(const short8*)(qkv + (size_t)(b * S_LEN + t * 64 + kp * 2 + p) * rstride + 2048 + h * 64 + c);
  };
  auto writeV = [&](int buf) {
    int kp = tid >> 4, sub = tid & 15;
    int p = sub & 1, c = (sub >> 1) * 8;
    uint32_t u0 = __shfl_xor(((const uint32_t*)&vr)[0], 1);
    uint32_t u1 = __shfl_xor(((const uint32_t*)&vr)[1], 1);
    uint32_t u2 = __shfl_xor(((const uint32_t*)&vr)[2], 1);
    uint32_t u3 = __shfl_xor(((const uint32_t*)&vr)[3], 1);
    unsigned short ov[8];
    ((uint32_t*)ov)[0] = u0; ((uint32_t*)ov)[1] = u1;
    ((uint32_t*)ov)[2] = u2; ((uint32_t*)ov)[3] = u3;
    const unsigned short* own = (const unsigned short*)&vr;
#pragma unroll
    for (int j = 0; j < 4; ++j) {
      int d = c + (p ? 4 : 0) + j;
      unsigned short lo = p ? ov[4 + j] : own[j];
      unsigned short hi = p ? own[4 + j] : ov[j];
      uint32_t packed = (uint32_t)lo | ((uint32_t)hi << 16);
      int kps = kp ^ (((d >> 2) & 7) << 2);
      ((uint32_t*)(&lV[buf][0]))[d * 36 + kps] = packed;
    }
  };

  stageK(0, 0);
  loadV(0);
  writeV(0);
  __syncthreads();

  for (int t = 0; t < ntiles; ++t) {
    const int cur = t & 1, nxt = cur ^ 1;
    const bool more = (t + 1 < ntiles);
    if (more) { stageK(nxt, t + 1); loadV(t + 1); }  // issue-early

    // QK^T swapped: mfma(A=K, B=Q) -> lane holds q=l15, k = jf*16+lg*4+r
    f32x4 sf[4] = {};
    __builtin_amdgcn_s_setprio(1);
#pragma unroll
    for (int ks = 0; ks < 2; ++ks) {
#pragma unroll
      for (int jf = 0; jf < 4; ++jf) {
        int krow = jf * 16 + l15;
        int g = krow * 128 + ks * 64 + lg * 16;
        int a = g ^ ((krow & 7) << 4);
        short8 kb = *(const short8*)((const char*)(&lK[cur][0]) + a);
        sf[jf] = __builtin_amdgcn_mfma_f32_16x16x32_bf16(kb, qf[ks], sf[jf], 0, 0, 0);
      }
    }
    __builtin_amdgcn_s_setprio(0);

    // online softmax (log2 domain), defer-max
    const int kv = t * 64;
    const bool dg = (kv + 63 > qb + w * 16);   // any masking for this wave?
    const int qglob = qb + w * 16 + l15;
    float pv[4][4];
    float mx = -3e38f;
#pragma unroll
    for (int jf = 0; jf < 4; ++jf)
#pragma unroll
      for (int r = 0; r < 4; ++r) {
        float v = sf[jf][r] * SCL;
        if (dg) {
          int kglob = kv + jf * 16 + lg * 4 + r;
          if (kglob > qglob) v = -3e38f;
        }
        pv[jf][r] = v;
        mx = fmaxf(mx, v);
      }
    mx = fmaxf(mx, __shfl_xor(mx, 16));
    mx = fmaxf(mx, __shfl_xor(mx, 32));
    if (!__all(mx - mrun <= 8.0f)) {
      float mn = fmaxf(mrun, mx);
      float alpha = exp2f(mrun - mn);
      mrun = mn;
      float ar[4];
#pragma unroll
      for (int r = 0; r < 4; ++r) ar[r] = __shfl(alpha, lg * 4 + r, 16);
#pragma unroll
      for (int j = 0; j < 4; ++j)
#pragma unroll
        for (int r = 0; r < 4; ++r)
          oacc[j][r] *= ar[r];
      lrun *= alpha;
    }
    float ps = 0.f;
#pragma unroll
    for (int jf = 0; jf < 4; ++jf)
#pragma unroll
      for (int r = 0; r < 4; ++r) {
        float e = exp2f(pv[jf][r] - mrun);
        pv[jf][r] = e;
        ps += e;
      }
    ps += __shfl_xor(ps, 16);
    ps += __shfl_xor(ps, 32);
    lrun += ps;

    // P -> per-wave LDS (packed cvt_pk writes)
    unsigned short* pw = &lP[w][0];
#pragma unroll
    for (int jf = 0; jf < 4; ++jf) {
      union { uint32_t u[2]; u16x4 v; } pk;
      pk.u[0] = pk2bf(pv[jf][0], pv[jf][1]);
      pk.u[1] = pk2bf(pv[jf][2], pv[jf][3]);
      *(u16x4*)(pw + l15 * 72 + jf * 16 + lg * 4) = pk.v;
    }

    // PV
    __builtin_amdgcn_s_setprio(1);
#pragma unroll
    for (int ks = 0; ks < 2; ++ks) {
      short8 pa = *(const short8*)(pw + l15 * 72 + ks * 32 + lg * 8);
      int B = ks * 16 + lg * 4;
#pragma unroll
      for (int j = 0; j < 4; ++j) {
        int d = j * 16 + l15;
        int fs = ((d >> 2) & 7) << 2;
        short8 vb = *(const short8*)((const char*)(&lV[cur][0]) + d * 144 + 4 * (B ^ fs));
        oacc[j] = __builtin_amdgcn_mfma_f32_16x16x32_bf16(pa, vb, oacc[j], 0, 0, 0);
      }
    }
    __builtin_amdgcn_s_setprio(0);

    if (more) writeV(nxt);   // write-late
    __syncthreads();
  }

  float lrow[4];
#pragma unroll
  for (int r = 0; r < 4; ++r) lrow[r] = __shfl(lrun, lg * 4 + r, 16);
#pragma unroll
  for (int j = 0; j < 4; ++j)
#pragma unroll
    for (int r = 0; r < 4; ++r) {
      int qrow = qb + w * 16 + lg * 4 + r;
      float v = oacc[j][r] / lrow[r];
      O[(size_t)(b * S_LEN + qrow) * 1024 + h * 64 + j * 16 + l15] = f2bf(v);
    }
}

extern "C" void kernel_launch(void* const* d_in, const int* in_sizes, int n_in,
                              void* d_out, int out_size, void* d_ws, size_t ws_size,
                              hipStream_t stream) {
  const float* x  = (const float*)d_in[0];
  const int* pos  = (const int*)d_in[1];
  const float* wq = (const float*)d_in[2];
  const float* wk = (const float*)d_in[3];
  const float* wv = (const float*)d_in[4];
  const float* wo = (const float*)d_in[5];
  float* out = (float*)d_out;

  char* ws = (char*)d_ws;
  unsigned short* xb   = (unsigned short*)(ws);
  unsigned short* wqkv = (unsigned short*)(ws + (size_t)16 * 1024 * 1024);
  unsigned short* wob  = (unsigned short*)(ws + (size_t)22 * 1024 * 1024);
  unsigned short* qkv  = (unsigned short*)(ws + (size_t)24 * 1024 * 1024);
  unsigned short* ob   = (unsigned short*)(ws + (size_t)72 * 1024 * 1024);
  float* tab = (float*)xb;  // reuse xb after gemm1

  k_cvt<<<8192, 256, 0, stream>>>(x, xb, 8192 * 1024 / 4);
  k_cvt4<<<4096, 256, 0, stream>>>(wq, wk, wv, wo, wqkv);

  // fused QKV projection
  k_gemm_nt<0><<<1536, 256, 0, stream>>>(xb, wqkv, qkv, 1024, 3072, 24);

  k_tab<<<256, 256, 0, stream>>>(pos, tab);
  k_rope<<<8192, 256, 0, stream>>>(qkv, tab);

  // causal flash attention
  k_attn<<<1024, 512, 0, stream>>>(qkv, ob);

  // output projection
  k_gemm_nt<1><<<512, 256, 0, stream>>>(ob, wob, out, 1024, 1024, 8);
}

// Round 7
// 310.289 us; speedup vs baseline: 1.7096x; 1.1730x over previous
//
#include <hip/hip_runtime.h>
#include <hip/hip_bf16.h>
#include <stdint.h>

#define S_LEN 2048
#define NHEAD 16
#define BATCH 4

typedef __attribute__((ext_vector_type(8))) short short8;
typedef __attribute__((ext_vector_type(4))) float f32x4;
typedef __attribute__((ext_vector_type(4))) unsigned short u16x4;
typedef __attribute__((ext_vector_type(2))) unsigned short u16x2;

__device__ __forceinline__ unsigned short f2bf(float f) {
  union { float f; uint32_t u; } a; a.f = f;
  uint32_t r = (a.u + 0x7fff + ((a.u >> 16) & 1)) >> 16;
  return (unsigned short)r;
}
__device__ __forceinline__ float bf2f(unsigned short u) {
  union { uint32_t u; float f; } a; a.u = ((uint32_t)u) << 16;
  return a.f;
}
__device__ __forceinline__ uint32_t pk2bf(float a, float b) {
  union { __hip_bfloat162 h; uint32_t u; } cv;
  cv.h = __float22bfloat162_rn(float2{a, b});
  return cv.u;
}

__device__ __forceinline__ void gload16(const void* g, void* l) {
  __builtin_amdgcn_global_load_lds(
      (const __attribute__((address_space(1))) void*)g,
      (__attribute__((address_space(3))) void*)l, 16, 0, 0);
}

// ---------------- fp32 -> bf16 convert ----------------
__global__ void k_cvt(const float* __restrict__ src, unsigned short* __restrict__ dst, int n4) {
  int i = blockIdx.x * blockDim.x + threadIdx.x;
  if (i < n4) {
    float4 v = ((const float4*)src)[i];
    union { uint32_t u[2]; u16x4 v; } o;
    o.u[0] = pk2bf(v.x, v.y);
    o.u[1] = pk2bf(v.z, v.w);
    ((u16x4*)dst)[i] = o.v;
  }
}

__global__ void k_cvt4(const float* __restrict__ s0, const float* __restrict__ s1,
                       const float* __restrict__ s2, const float* __restrict__ s3,
                       unsigned short* __restrict__ dst) {
  int i = blockIdx.x * 256 + threadIdx.x;
  int r = i >> 18;
  const float* s = r == 0 ? s0 : r == 1 ? s1 : r == 2 ? s2 : s3;
  float4 v = ((const float4*)s)[i & 0x3FFFF];
  union { uint32_t u[2]; u16x4 v; } o;
  o.u[0] = pk2bf(v.x, v.y);
  o.u[1] = pk2bf(v.z, v.w);
  ((u16x4*)dst)[i] = o.v;
}

// ---------------- NT GEMM: C[M,N] = A[M,K] * B[N,K]^T, XCD-swizzled 1D grid ----------
template<int OUTF32>
__global__ __launch_bounds__(256) void k_gemm_nt(
    const unsigned short* __restrict__ A, const unsigned short* __restrict__ B,
    void* __restrict__ Cp, int K, int ldc, int gx)
{
  __shared__ unsigned short lA[128 * 64];
  __shared__ unsigned short lB[128 * 64];
  const int tid = threadIdx.x;
  const int w = tid >> 6, lane = tid & 63;
  const int wm = w >> 1, wn = w & 1;
  const int l15 = lane & 15, lg = lane >> 4;
  const int nwg = (int)gridDim.x, slot = (int)blockIdx.x;
  const int f = (slot & 7) * (nwg >> 3) + (slot >> 3);
  const int row0 = (f / gx) * 128, col0 = (f % gx) * 128;

  f32x4 acc[4][4] = {};
  const size_t rsb = (size_t)K * 2;

  for (int k0 = 0; k0 < K; k0 += 64) {
#pragma unroll
    for (int it = 0; it < 4; ++it) {
      int fb = w * 4096 + it * 1024 + lane * 16;
      int r = fb >> 7, cb = fb & 127;
      gload16((const char*)A + (size_t)(row0 + r) * rsb + k0 * 2 + cb,
              (char*)lA + (w * 4096 + it * 1024));
      gload16((const char*)B + (size_t)(col0 + r) * rsb + k0 * 2 + cb,
              (char*)lB + (w * 4096 + it * 1024));
    }
    __syncthreads();
#pragma unroll
    for (int ks = 0; ks < 2; ++ks) {
      short8 af[4], bg[4];
#pragma unroll
      for (int i = 0; i < 4; ++i) {
        int rowa = wm * 64 + i * 16 + l15;
        af[i] = *(const short8*)((const char*)lA + rowa * 128 + ks * 64 + lg * 16);
        int rowb = wn * 64 + i * 16 + l15;
        bg[i] = *(const short8*)((const char*)lB + rowb * 128 + ks * 64 + lg * 16);
      }
#pragma unroll
      for (int i = 0; i < 4; ++i)
#pragma unroll
        for (int j = 0; j < 4; ++j)
          acc[i][j] = __builtin_amdgcn_mfma_f32_16x16x32_bf16(af[i], bg[j], acc[i][j], 0, 0, 0);
    }
    __syncthreads();
  }

#pragma unroll
  for (int i = 0; i < 4; ++i)
#pragma unroll
    for (int j = 0; j < 4; ++j)
#pragma unroll
      for (int r = 0; r < 4; ++r) {
        int row = row0 + wm * 64 + i * 16 + lg * 4 + r;
        int col = col0 + wn * 64 + j * 16 + l15;
        float v = acc[i][j][r];
        if (OUTF32) ((float*)Cp)[(size_t)row * ldc + col] = v;
        else ((unsigned short*)Cp)[(size_t)row * ldc + col] = f2bf(v);
      }
}

// ---------------- RoPE tables (Q pre-scaled by 1/sqrt(dk)*log2e) + apply ----------------
__global__ void k_tab(const int* __restrict__ pos, float* __restrict__ tab) {
  int i = blockIdx.x * 256 + threadIdx.x;   // 65536 = s*32 + p
  int s = i >> 5, p = i & 31;
  float fp = (float)pos[s];
  float inv = exp2f(-(float)p * 0.41524101186092029f);
  float ang = fp * inv;
  float sn, cs;
  __sincosf(ang, &sn, &cs);
  const float SCL = 0.18033688011112042f;   // (1/8) * log2(e)
  ((float2*)tab)[i] = float2{cs * SCL, sn * SCL};       // Q table
  ((float2*)tab)[65536 + i] = float2{cs, sn};           // K table
}

__global__ void k_rope(unsigned short* __restrict__ qkv, const float* __restrict__ tab) {
  int idx = blockIdx.x * 256 + threadIdx.x;
  int row = idx >> 8;
  int rem = idx & 255;
  int which = rem >> 7;        // 0=Q (scaled table), 1=K
  int cq = rem & 127;
  int p0 = (cq * 4) & 31;
  int s = row & (S_LEN - 1);
  const float4* tb = (const float4*)(tab + ((which << 17) + (s * 32 + p0) * 2));
  float4 t0 = tb[0], t1 = tb[1];
  size_t off = (size_t)row * 3072 + which * 1024 + cq * 8;
  short8 v = *(short8*)(qkv + off);
  float x0 = bf2f((unsigned short)v[0]), x1 = bf2f((unsigned short)v[1]);
  float x2 = bf2f((unsigned short)v[2]), x3 = bf2f((unsigned short)v[3]);
  float x4 = bf2f((unsigned short)v[4]), x5 = bf2f((unsigned short)v[5]);
  float x6 = bf2f((unsigned short)v[6]), x7 = bf2f((unsigned short)v[7]);
  union { uint32_t u[4]; short8 v; } o;
  o.u[0] = pk2bf(t0.x * x0 - t0.y * x1, t0.y * x0 + t0.x * x1);
  o.u[1] = pk2bf(t0.z * x2 - t0.w * x3, t0.w * x2 + t0.z * x3);
  o.u[2] = pk2bf(t1.x * x4 - t1.y * x5, t1.y * x4 + t1.x * x5);
  o.u[3] = pk2bf(t1.z * x6 - t1.w * x7, t1.w * x6 + t1.z * x7);
  *(short8*)(qkv + off) = o.v;
}

// ---------------- causal flash attention: paired q-tiles, reg-resident P -----------
// 512 blocks x 512 threads. Block (bh, p) does q-tiles (15-p)*128 then p*128 (34 KV-tiles).
// Wave w owns q-rows [qb + w*16, qb + w*16 + 16).
__global__ __launch_bounds__(512) void k_attn(const unsigned short* __restrict__ qkv,
                                              unsigned short* __restrict__ O) {
  __shared__ unsigned short lK[2][64 * 64];  // [krow][dk] bytes, XOR-swizzled
  __shared__ uint32_t lV32[2][64 * 36];      // V^T [d][col32], sigma-ordered + swizzled

  const int tid = threadIdx.x, w = tid >> 6, lane = tid & 63;
  const int l15 = lane & 15, lg = lane >> 4;
  const int slot = (int)blockIdx.x;
  const int f0 = (slot & 7) * 64 + (slot >> 3);  // XCD k: f0 in [64k, 64k+64)
  const int bh = f0 >> 3, qp = f0 & 7;           // 8 bh per XCD -> KV set = 4MB = one L2
  const int b = bh >> 4, h = bh & 15;
  const size_t rstride = 3072;

  short8 vr;  // V tile staged in regs (issue-early / write-late)

  auto stageK = [&](int buf, int t) {
    int fb = tid * 16;
    int r = fb >> 7;
    int cb = (fb ^ ((r & 7) << 4)) & 127;
    gload16((const char*)qkv + ((size_t)(b * S_LEN + t * 64 + r) * rstride + 1024 + h * 64) * 2 + cb,
            (char*)(&lK[buf][0]) + fb);
  };
  auto loadV = [&](int t) {
    int kp = tid >> 4, sub = tid & 15;
    int pp = sub & 1, c = (sub >> 1) * 8;
    vr = *(const short8*)(qkv + (size_t)(b * S_LEN + t * 64 + kp * 2 + pp) * rstride + 2048 + h * 64 + c);
  };
  // store V^T at sigma-permuted k columns: kv = 32ks+16jf+4lgv+r -> col = 32ks+8lgv+4jf+r
  auto writeV = [&](int buf) {
    int kp = tid >> 4, sub = tid & 15;
    int pp = sub & 1, c = (sub >> 1) * 8;
    uint32_t u0 = __shfl_xor(((const uint32_t*)&vr)[0], 1);
    uint32_t u1 = __shfl_xor(((const uint32_t*)&vr)[1], 1);
    uint32_t u2 = __shfl_xor(((const uint32_t*)&vr)[2], 1);
    uint32_t u3 = __shfl_xor(((const uint32_t*)&vr)[3], 1);
    unsigned short ov[8];
    ((uint32_t*)ov)[0] = u0; ((uint32_t*)ov)[1] = u1;
    ((uint32_t*)ov)[2] = u2; ((uint32_t*)ov)[3] = u3;
    const unsigned short* own = (const unsigned short*)&vr;
    // u32 col for kv pair (2kp, 2kp+1):
    int colk = ((kp >> 4) << 4) | (((kp >> 1) & 3) << 2) | (((kp >> 3) & 1) << 1) | (kp & 1);
#pragma unroll
    for (int j = 0; j < 4; ++j) {
      int d = c + (pp ? 4 : 0) + j;
      unsigned short lo = pp ? ov[4 + j] : own[j];
      unsigned short hi = pp ? own[4 + j] : ov[j];
      uint32_t packed = (uint32_t)lo | ((uint32_t)hi << 16);
      int colS = colk ^ (((d >> 3) & 7) << 2);
      lV32[buf][d * 36 + colS] = packed;
    }
  };

  for (int seg = 0; seg < 2; ++seg) {
    const int qb = (seg == 0 ? (15 - qp) : qp) * 128;
    const int ntiles = (qb >> 6) + 2;

    // Q fragments (B-operand, table-prescaled): lane l15 = q-row, lg = dk-slice
    short8 qf[2];
    {
      int qrow = qb + w * 16 + l15;
      const unsigned short* qpt = qkv + (size_t)(b * S_LEN + qrow) * rstride + h * 64 + lg * 8;
      qf[0] = *(const short8*)qpt;
      qf[1] = *(const short8*)(qpt + 32);
    }

    float mrun = -3e38f, lrun = 0.f;
    f32x4 oacc[4] = {};

    stageK(0, 0);
    loadV(0);
    writeV(0);
    __syncthreads();

    for (int t = 0; t < ntiles; ++t) {
      const int cur = t & 1, nxt = cur ^ 1;
      const bool more = (t + 1 < ntiles);
      if (more) { stageK(nxt, t + 1); loadV(t + 1); }  // issue-early

      // QK^T swapped: mfma(A=K, B=Q) -> lane holds q=l15, k-slot = jf*16+lg*4+r
      f32x4 sf[4] = {};
      __builtin_amdgcn_s_setprio(1);
#pragma unroll
      for (int ks = 0; ks < 2; ++ks) {
#pragma unroll
        for (int jf = 0; jf < 4; ++jf) {
          int krow = jf * 16 + l15;
          int g = krow * 128 + ks * 64 + lg * 16;
          int a = g ^ ((krow & 7) << 4);
          short8 kb = *(const short8*)((const char*)(&lK[cur][0]) + a);
          sf[jf] = __builtin_amdgcn_mfma_f32_16x16x32_bf16(kb, qf[ks], sf[jf], 0, 0, 0);
        }
      }
      __builtin_amdgcn_s_setprio(0);

      // online softmax (log2 domain, pre-scaled), defer-max
      const int kv = t * 64;
      const bool dg = (kv + 63 > qb + w * 16);
      const int qglob = qb + w * 16 + l15;
      float pv[4][4];
      float mx = -3e38f;
#pragma unroll
      for (int jf = 0; jf < 4; ++jf)
#pragma unroll
        for (int r = 0; r < 4; ++r) {
          float v = sf[jf][r];
          if (dg) {
            int kglob = kv + jf * 16 + lg * 4 + r;
            if (kglob > qglob) v = -3e38f;
          }
          pv[jf][r] = v;
          mx = fmaxf(mx, v);
        }
      mx = fmaxf(mx, __shfl_xor(mx, 16));
      mx = fmaxf(mx, __shfl_xor(mx, 32));
      if (!__all(mx - mrun <= 8.0f)) {
        float mn = fmaxf(mrun, mx);
        float alpha = exp2f(mrun - mn);
        mrun = mn;
#pragma unroll
        for (int j = 0; j < 4; ++j)
#pragma unroll
          for (int r = 0; r < 4; ++r)
            oacc[j][r] *= alpha;     // rows are d; alpha is per-lane q — no shuffle
        lrun *= alpha;
      }
      float ps = 0.f;
#pragma unroll
      for (int jf = 0; jf < 4; ++jf)
#pragma unroll
        for (int r = 0; r < 4; ++r) {
          float e = exp2f(pv[jf][r] - mrun);
          pv[jf][r] = e;
          ps += e;
        }
      ps += __shfl_xor(ps, 16);
      ps += __shfl_xor(ps, 32);
      lrun += ps;

      // PV swapped: O^T[d][q] += V^T[d][k] * P^T[k][q]; P^T B-frag comes straight
      // from pv regs (sigma ordering), V^T A-frag from lV32.
      __builtin_amdgcn_s_setprio(1);
#pragma unroll
      for (int ks = 0; ks < 2; ++ks) {
        union { uint32_t u[4]; short8 v; } pb;
        pb.u[0] = pk2bf(pv[2 * ks][0], pv[2 * ks][1]);
        pb.u[1] = pk2bf(pv[2 * ks][2], pv[2 * ks][3]);
        pb.u[2] = pk2bf(pv[2 * ks + 1][0], pv[2 * ks + 1][1]);
        pb.u[3] = pk2bf(pv[2 * ks + 1][2], pv[2 * ks + 1][3]);
#pragma unroll
        for (int j = 0; j < 4; ++j) {
          int d = j * 16 + l15;
          int colS = (ks * 16 + lg * 4) ^ (((d >> 3) & 7) << 2);
          short8 vb = *(const short8*)(&lV32[cur][d * 36 + colS]);
          oacc[j] = __builtin_amdgcn_mfma_f32_16x16x32_bf16(vb, pb.v, oacc[j], 0, 0, 0);
        }
      }
      __builtin_amdgcn_s_setprio(0);

      if (more) writeV(nxt);  // write-late
      __syncthreads();
    }

    // O write: lane owns one q-row entirely; d = j*16 + lg*4 + r (contiguous quads)
    float rinv = __builtin_amdgcn_rcpf(lrun);
    int qrow = qb + w * 16 + l15;
    unsigned short* orow = O + (size_t)(b * S_LEN + qrow) * 1024 + h * 64;
#pragma unroll
    for (int j = 0; j < 4; ++j) {
      union { uint32_t u[2]; u16x4 v; } ow;
      ow.u[0] = pk2bf(oacc[j][0] * rinv, oacc[j][1] * rinv);
      ow.u[1] = pk2bf(oacc[j][2] * rinv, oacc[j][3] * rinv);
      *(u16x4*)(orow + j * 16 + lg * 4) = ow.v;
    }
  }
}

extern "C" void kernel_launch(void* const* d_in, const int* in_sizes, int n_in,
                              void* d_out, int out_size, void* d_ws, size_t ws_size,
                              hipStream_t stream) {
  const float* x  = (const float*)d_in[0];
  const int* pos  = (const int*)d_in[1];
  const float* wq = (const float*)d_in[2];
  const float* wk = (const float*)d_in[3];
  const float* wv = (const float*)d_in[4];
  const float* wo = (const float*)d_in[5];
  float* out = (float*)d_out;

  char* ws = (char*)d_ws;
  unsigned short* xb   = (unsigned short*)(ws);
  unsigned short* wqkv = (unsigned short*)(ws + (size_t)16 * 1024 * 1024);
  unsigned short* wob  = (unsigned short*)(ws + (size_t)22 * 1024 * 1024);
  unsigned short* qkv  = (unsigned short*)(ws + (size_t)24 * 1024 * 1024);
  unsigned short* ob   = (unsigned short*)(ws + (size_t)72 * 1024 * 1024);
  float* tab = (float*)xb;  // reuse xb after gemm1 (1 MB: Q table + K table)

  k_cvt<<<8192, 256, 0, stream>>>(x, xb, 8192 * 1024 / 4);
  k_cvt4<<<4096, 256, 0, stream>>>(wq, wk, wv, wo, wqkv);

  // fused QKV projection
  k_gemm_nt<0><<<1536, 256, 0, stream>>>(xb, wqkv, qkv, 1024, 3072, 24);

  k_tab<<<256, 256, 0, stream>>>(pos, tab);
  k_rope<<<8192, 256, 0, stream>>>(qkv, tab);

  // causal flash attention (paired q-tiles)
  k_attn<<<512, 512, 0, stream>>>(qkv, ob);

  // output projection
  k_gemm_nt<1><<<512, 256, 0, stream>>>(ob, wob, out, 1024, 1024, 8);
}